// Round 14
// baseline (353.258 us; speedup 1.0000x reference)
//
#include <hip/hip_runtime.h>

#define V_N 4096
#define C_N 32
#define T_N 512

typedef float f32x4 __attribute__((ext_vector_type(4)));
typedef __bf16 bf16x8 __attribute__((ext_vector_type(8)));

__device__ inline f32x4 fma4(f32x4 a, float b, f32x4 c) {
    f32x4 r;
    r.x = fmaf(a.x, b, c.x); r.y = fmaf(a.y, b, c.y);
    r.z = fmaf(a.z, b, c.z); r.w = fmaf(a.w, b, c.w);
    return r;
}

// ---------------------------------------------------------------------------
// Zero tmpT+Gc (adjacent 32768 floats at ws[0..]) before k_rtpre's atomics.
__global__ __launch_bounds__(256) void k_zero(float* __restrict__ zz) {
    int i = (blockIdx.x * 256 + threadIdx.x) * 4;
    *(f32x4*)&zz[i] = (f32x4)0.f;
}

// ---------------------------------------------------------------------------
// Blocks 0..255: streaming x-pass (R11's proven spill-free body; the ONLY
// launch-bounds that doesn't spill this register set is (256,1) — R12/R13
// both spilled ~283MB scratch under tighter VGPR caps).
// Block = 16 v-planes (64KB each); wave w reads rows (w*16+j), j=0..15 —
// 16KB contiguous per wave per plane. c = w*8+(j>>1), t = (j&1)*256+l*4.
// Results accumulate via L2-resident atomicAdd into tmpT/Gc (128KB total;
// deletes the 33MB partial write + 33MB k_red read + one kernel node).
// Blocks 256..1279: Ve hi/lo split in MFMA A-fragment order.
__global__ __launch_bounds__(256, 1) void k_rtpre(const float* __restrict__ x,
                                                  const float* __restrict__ U1,
                                                  const float* __restrict__ U2,
                                                  const float* __restrict__ U3,
                                                  float* __restrict__ tmpT,
                                                  float* __restrict__ Gc,
                                                  const float* __restrict__ Ve,
                                                  __bf16* __restrict__ VeHi,
                                                  __bf16* __restrict__ VeLo) {
    __shared__ f32x4 lsum[2][4][2][64];   // [buf][wave][t-half][lane] = 16KB

    if (blockIdx.x >= 256) {
        // Ve split: o -> tile, lane lp, elem e:
        //   t=(tile>>4)*16+(lp&15), k=(tile&15)*32+(lp>>4)*8+e
        int o = (blockIdx.x - 256) * 256 + threadIdx.x;   // 0..262143
        int e = o & 7, lp = (o >> 3) & 63, tile = o >> 9;
        int kk = tile & 15, tt = tile >> 4;
        int t = tt * 16 + (lp & 15);
        int k = kk * 32 + (lp >> 4) * 8 + e;
        float v = Ve[(size_t)t * T_N + k];
        __bf16 h = (__bf16)v;
        VeHi[o] = h;
        VeLo[o] = (__bf16)(v - (float)h);
        return;
    }

    const int vc = blockIdx.x;            // 0..255, 16 v each
    const int tid = threadIdx.x;
    const int w = tid >> 6;               // wave 0..3
    const int l = tid & 63;               // lane
    const int v0 = vc * 16;

    float u3loc[8];
#pragma unroll
    for (int i = 0; i < 8; ++i) u3loc[i] = U3[w * 8 + i];

    f32x4 accT[8][2];
    f32x4 gacc[8][2];
#pragma unroll
    for (int i = 0; i < 8; ++i)
#pragma unroll
        for (int s = 0; s < 2; ++s) {
            accT[i][s] = (f32x4)0.f;
            gacc[i][s] = (f32x4)0.f;
        }

    const float* xplane0 = x + (size_t)v0 * (C_N * T_N);
#pragma unroll 1
    for (int vi = 0; vi < 16; ++vi) {
        const float* xp = xplane0 + (size_t)vi * (C_N * T_N);
        float u1 = U1[v0 + vi];
        int buf = vi & 1;
        f32x4 racc0 = (f32x4)0.f, racc1 = (f32x4)0.f;
#pragma unroll
        for (int j = 0; j < 16; ++j) {
            f32x4 xv = *(const f32x4*)(xp + (size_t)(w * 16 + j) * 256 + l * 4);
            int i = j >> 1;
            if ((j & 1) == 0) {
                accT[i][0] = fma4(xv, u1, accT[i][0]);
                racc0 = fma4(xv, u3loc[i], racc0);
            } else {
                accT[i][1] = fma4(xv, u1, accT[i][1]);
                racc1 = fma4(xv, u3loc[i], racc1);
            }
        }
        lsum[buf][w][0][l] = racc0;
        lsum[buf][w][1][l] = racc1;
        __syncthreads();
        f32x4 rhs0 = (lsum[buf][0][0][l] + lsum[buf][1][0][l]) +
                     (lsum[buf][2][0][l] + lsum[buf][3][0][l]);
        f32x4 rhs1 = (lsum[buf][0][1][l] + lsum[buf][1][1][l]) +
                     (lsum[buf][2][1][l] + lsum[buf][3][1][l]);
        float u2loc[8];
#pragma unroll
        for (int i = 0; i < 8; ++i)
            u2loc[i] = U2[(size_t)(w * 8 + i) * V_N + v0 + vi];
#pragma unroll
        for (int i = 0; i < 8; ++i) {
            gacc[i][0] = fma4(rhs0, u2loc[i], gacc[i][0]);
            gacc[i][1] = fma4(rhs1, u2loc[i], gacc[i][1]);
        }
    }

    // ---- accumulate into L2-resident tmpT/Gc (128KB) via atomics
#pragma unroll
    for (int i = 0; i < 8; ++i)
#pragma unroll
        for (int s = 0; s < 2; ++s) {
            int base = (w * 8 + i) * T_N + s * 256 + l * 4;
#pragma unroll
            for (int q = 0; q < 4; ++q) {
                atomicAdd(&tmpT[base + q], accT[i][s][q]);
                atomicAdd(&Gc[base + q], gacc[i][s][q]);
            }
        }
}

// ---------------------------------------------------------------------------
// P[s][r] = sum_c Gc[c][s] * tmpT[c][r]    (K=32 tiny GEMM, fp32)
__global__ __launch_bounds__(256) void k_P2(const float* __restrict__ Gc,
                                            const float* __restrict__ tmpT,
                                            float* __restrict__ P) {
    __shared__ float Gs[32][64];
    __shared__ float Ts[32][64];
    int rbase = blockIdx.x * 64, sbase = blockIdx.y * 64;
    int tid = threadIdx.x;
    int tx = tid & 15, ty = tid >> 4;
    for (int i = tid; i < 2048; i += 256) {
        int cc = i >> 6, j = i & 63;
        Gs[cc][j] = Gc[cc * T_N + sbase + j];
        Ts[cc][j] = tmpT[cc * T_N + rbase + j];
    }
    __syncthreads();
    float acc[4][4] = {};
#pragma unroll
    for (int cc = 0; cc < 32; ++cc) {
        float a[4], b[4];
#pragma unroll
        for (int i = 0; i < 4; ++i) a[i] = Gs[cc][ty * 4 + i];
#pragma unroll
        for (int j = 0; j < 4; ++j) b[j] = Ts[cc][tx * 4 + j];
#pragma unroll
        for (int i = 0; i < 4; ++i)
#pragma unroll
            for (int j = 0; j < 4; ++j) acc[i][j] = fmaf(a[i], b[j], acc[i][j]);
    }
#pragma unroll
    for (int i = 0; i < 4; ++i) {
        f32x4 vv = {acc[i][0], acc[i][1], acc[i][2], acc[i][3]};
        *(f32x4*)&P[(size_t)(sbase + ty * 4 + i) * T_N + rbase + tx * 4] = vv;
    }
}

// ---------------------------------------------------------------------------
// Fused: per block (c, 32-wide r tile), all t (512 blocks, 2 blocks/CU):
//   S[s][r] = sigmoid(P[s][r] + be[c][s][r])   (bf16, LDS 32KB, XOR-swizzled)
//   E[t][r] = sum_s (VeHi+VeLo)[t][s] * S[s][r]  via MFMA 16x16x32 bf16
//   out[c][t][r] = softmax_t(E)
// 8 waves = 4(t) x 2(r); per wave 128t x 16r = 8x1 tiles.
__global__ __launch_bounds__(512, 4) void k_fused(const float* __restrict__ P,
                                                  const float* __restrict__ be,
                                                  const __bf16* __restrict__ VeHi,
                                                  const __bf16* __restrict__ VeLo,
                                                  float* __restrict__ out) {
    __shared__ __bf16 S[32][512];   // 32KB: S^T layout [r][s], swizzled
    const int rbase = blockIdx.x * 32;
    const int c = blockIdx.y;
    const int tid = threadIdx.x;
    const size_t cTT = (size_t)c * T_N * T_N;

    // ---- phase 1: sigmoid once per element (f32x4 loads), S^T bf16 swizzled
    {
        int r4 = (tid & 7) * 4;
        int s0 = tid >> 3;          // 0..63
        for (int i = 0; i < 8; ++i) {
            int s = i * 64 + s0;
            size_t off = (size_t)s * T_N + rbase + r4;
            f32x4 pv = *(const f32x4*)&P[off];
            f32x4 bv = *(const f32x4*)&be[cTT + off];
#pragma unroll
            for (int j = 0; j < 4; ++j) {
                float vv = pv[j] + bv[j];
                float sg = 1.0f / (1.0f + __expf(-vv));
                int rl = r4 + j;
                S[rl][s ^ ((rl & 7) << 3)] = (__bf16)sg;
            }
        }
    }
    __syncthreads();

    const int lane = tid & 63;
    const int w = tid >> 6;     // 0..7
    const int wt = w & 3;       // t-wave: 128 rows each
    const int wr = w >> 2;      // r-wave: 16 cols each
    const int lhi = lane >> 4;  // 0..3
    const int llo = lane & 15;

    const bf16x8* fragHi = (const bf16x8*)VeHi;
    const bf16x8* fragLo = (const bf16x8*)VeLo;

    f32x4 acc[8];
#pragma unroll
    for (int mi = 0; mi < 8; ++mi) acc[mi] = (f32x4)0.f;

    // ---- phase 2: K loop (s), A = packed Ve frags (L2-hot), B from LDS
    for (int k0 = 0; k0 < T_N; k0 += 32) {
        int rr = wr * 16 + llo;
        int g = (k0 >> 3) + lhi;
        bf16x8 b = *(const bf16x8*)&S[rr][(g ^ (rr & 7)) << 3];
#pragma unroll
        for (int mi = 0; mi < 8; ++mi) {
            int tile = (wt * 8 + mi) * 16 + (k0 >> 5);
            bf16x8 ah = fragHi[tile * 64 + lane];
            bf16x8 al = fragLo[tile * 64 + lane];
            acc[mi] = __builtin_amdgcn_mfma_f32_16x16x32_bf16(ah, b, acc[mi], 0, 0, 0);
            acc[mi] = __builtin_amdgcn_mfma_f32_16x16x32_bf16(al, b, acc[mi], 0, 0, 0);
        }
    }
    __syncthreads();            // done with S; reuse as reduction buffers

    float* red = (float*)&S[0][0];  // [0..127]=max, [128..255]=sum
    float gmax, gsum;

    // ---- phase 3a: column max over t
    {
        float m = -3.4e38f;
#pragma unroll
        for (int mi = 0; mi < 8; ++mi)
#pragma unroll
            for (int q = 0; q < 4; ++q) m = fmaxf(m, acc[mi][q]);
        m = fmaxf(m, __shfl_xor(m, 16));
        m = fmaxf(m, __shfl_xor(m, 32));
        if (lane < 16) red[wt * 32 + wr * 16 + llo] = m;
    }
    __syncthreads();
    {
        int col = wr * 16 + llo;
        gmax = fmaxf(fmaxf(red[col], red[32 + col]),
                     fmaxf(red[64 + col], red[96 + col]));
    }
    // ---- phase 3b: exp + column sum
    {
        float ssum = 0.f;
#pragma unroll
        for (int mi = 0; mi < 8; ++mi)
#pragma unroll
            for (int q = 0; q < 4; ++q) {
                float e = __expf(acc[mi][q] - gmax);
                acc[mi][q] = e;
                ssum += e;
            }
        ssum += __shfl_xor(ssum, 16);
        ssum += __shfl_xor(ssum, 32);
        if (lane < 16) red[128 + wt * 32 + wr * 16 + llo] = ssum;
    }
    __syncthreads();
    {
        int col = wr * 16 + llo;
        gsum = 1.0f / (red[128 + col] + red[128 + 32 + col] +
                       red[128 + 64 + col] + red[128 + 96 + col]);
    }
    // ---- phase 3c: write normalized output
    {
        int rg = rbase + wr * 16 + llo;
#pragma unroll
        for (int mi = 0; mi < 8; ++mi)
#pragma unroll
            for (int q = 0; q < 4; ++q) {
                int t = wt * 128 + mi * 16 + lhi * 4 + q;
                out[cTT + (size_t)t * T_N + rg] = acc[mi][q] * gsum;
            }
    }
}

// ---------------------------------------------------------------------------
extern "C" void kernel_launch(void* const* d_in, const int* in_sizes, int n_in,
                              void* d_out, int out_size, void* d_ws, size_t ws_size,
                              hipStream_t stream) {
    const float* x  = (const float*)d_in[0];
    const float* U1 = (const float*)d_in[1];
    const float* U2 = (const float*)d_in[2];
    const float* U3 = (const float*)d_in[3];
    const float* be = (const float*)d_in[4];
    const float* Ve = (const float*)d_in[5];
    float* out = (float*)d_out;

    float* ws    = (float*)d_ws;
    float* tmpT  = ws;                        // 16384 floats
    float* Gc    = ws + 16384;                // 16384 (adjacent for k_zero)
    float* P     = ws + 32768;                // 262144
    __bf16* VeHi = (__bf16*)(ws + 294912);    // 262144 bf16 (131072 slots)
    __bf16* VeLo = (__bf16*)(ws + 425984);    // 262144 bf16
    // total ~557056 floats ~= 2.2 MB

    k_zero <<<32, 256, 0, stream>>>(ws);
    k_rtpre<<<256 + 1024, 256, 0, stream>>>(x, U1, U2, U3, tmpT, Gc, Ve, VeHi, VeLo);
    k_P2   <<<dim3(8, 8), 256, 0, stream>>>(Gc, tmpT, P);
    k_fused<<<dim3(16, C_N), 512, 0, stream>>>(P, be, VeHi, VeLo, out);
}

// Round 15
// 119.854 us; speedup vs baseline: 2.9474x; 2.9474x over previous
//
#include <hip/hip_runtime.h>

#define V_N 4096
#define C_N 32
#define T_N 512

typedef float f32x4 __attribute__((ext_vector_type(4)));
typedef __bf16 bf16x8 __attribute__((ext_vector_type(8)));

__device__ inline f32x4 fma4(f32x4 a, float b, f32x4 c) {
    f32x4 r;
    r.x = fmaf(a.x, b, c.x); r.y = fmaf(a.y, b, c.y);
    r.z = fmaf(a.z, b, c.z); r.w = fmaf(a.w, b, c.w);
    return r;
}

// ---------------------------------------------------------------------------
// Streaming x-pass — R11's proven spill-free kernel, UNTOUCHED and standalone.
// (R12/R13/R14 all regressed: merged-branch variants got VGPR-capped at
// 128/64 and spilled ~130-280MB scratch; atomics to small region are
// memory-side RMWs on this chip. Do not add branches or occupancy caps here.)
// Block = 16 v-planes (64KB each); wave w reads rows (w*16+j), j=0..15 —
// 16KB contiguous per wave per plane. c = w*8+(j>>1), t = (j&1)*256+l*4.
//   partT[vc][c][t] = sum_{vi} x[v,c,t]*U1[v]
//   partG[vc][c][t] = sum_{vi} rhs[v,t]*U2[c,v],  rhs = sum_c x*U3[c]
__global__ __launch_bounds__(256, 1) void k_rt(const float* __restrict__ x,
                                               const float* __restrict__ U1,
                                               const float* __restrict__ U2,
                                               const float* __restrict__ U3,
                                               float* __restrict__ partT,
                                               float* __restrict__ partG) {
    const int vc = blockIdx.x;            // 0..255, 16 v each
    const int tid = threadIdx.x;
    const int w = tid >> 6;               // wave 0..3
    const int l = tid & 63;               // lane
    const int v0 = vc * 16;

    __shared__ f32x4 lsum[2][4][2][64];   // [buf][wave][t-half][lane] = 16KB

    float u3loc[8];
#pragma unroll
    for (int i = 0; i < 8; ++i) u3loc[i] = U3[w * 8 + i];

    f32x4 accT[8][2];
    f32x4 gacc[8][2];
#pragma unroll
    for (int i = 0; i < 8; ++i)
#pragma unroll
        for (int s = 0; s < 2; ++s) {
            accT[i][s] = (f32x4)0.f;
            gacc[i][s] = (f32x4)0.f;
        }

    const float* xplane0 = x + (size_t)v0 * (C_N * T_N);
#pragma unroll 1
    for (int vi = 0; vi < 16; ++vi) {
        const float* xp = xplane0 + (size_t)vi * (C_N * T_N);
        float u1 = U1[v0 + vi];
        int buf = vi & 1;
        f32x4 racc0 = (f32x4)0.f, racc1 = (f32x4)0.f;
#pragma unroll
        for (int j = 0; j < 16; ++j) {
            f32x4 xv = *(const f32x4*)(xp + (size_t)(w * 16 + j) * 256 + l * 4);
            int i = j >> 1;
            if ((j & 1) == 0) {
                accT[i][0] = fma4(xv, u1, accT[i][0]);
                racc0 = fma4(xv, u3loc[i], racc0);
            } else {
                accT[i][1] = fma4(xv, u1, accT[i][1]);
                racc1 = fma4(xv, u3loc[i], racc1);
            }
        }
        lsum[buf][w][0][l] = racc0;
        lsum[buf][w][1][l] = racc1;
        __syncthreads();
        f32x4 rhs0 = (lsum[buf][0][0][l] + lsum[buf][1][0][l]) +
                     (lsum[buf][2][0][l] + lsum[buf][3][0][l]);
        f32x4 rhs1 = (lsum[buf][0][1][l] + lsum[buf][1][1][l]) +
                     (lsum[buf][2][1][l] + lsum[buf][3][1][l]);
        float u2loc[8];
#pragma unroll
        for (int i = 0; i < 8; ++i)
            u2loc[i] = U2[(size_t)(w * 8 + i) * V_N + v0 + vi];
#pragma unroll
        for (int i = 0; i < 8; ++i) {
            gacc[i][0] = fma4(rhs0, u2loc[i], gacc[i][0]);
            gacc[i][1] = fma4(rhs1, u2loc[i], gacc[i][1]);
        }
    }

    const size_t pbase = (size_t)vc * (C_N * T_N);
#pragma unroll
    for (int i = 0; i < 8; ++i)
#pragma unroll
        for (int s = 0; s < 2; ++s) {
            size_t off = pbase + (size_t)(w * 8 + i) * T_N + s * 256 + l * 4;
            *(f32x4*)&partT[off] = accT[i][s];
            *(f32x4*)&partG[off] = gacc[i][s];
        }
}

// ---------------------------------------------------------------------------
// Blocks 0..511: fixed-order reduce of 256 chunk-partials -> tmpT, Gc.
// Blocks 512..2559: Ve hi/lo split in MFMA A-fragment order (low-VGPR kernel,
// branch is safe here).
__global__ __launch_bounds__(128) void k_redpre(const float* __restrict__ partT,
                                                const float* __restrict__ partG,
                                                float* __restrict__ tmpT,
                                                float* __restrict__ Gc,
                                                const float* __restrict__ Ve,
                                                __bf16* __restrict__ VeHi,
                                                __bf16* __restrict__ VeLo) {
    if (blockIdx.x >= 512) {
        // Ve split: o -> tile, lane lp, elem e:
        //   t=(tile>>4)*16+(lp&15), k=(tile&15)*32+(lp>>4)*8+e
        int o = (blockIdx.x - 512) * 128 + threadIdx.x;   // 0..262143
        int e = o & 7, lp = (o >> 3) & 63, tile = o >> 9;
        int kk = tile & 15, tt = tile >> 4;
        int t = tt * 16 + (lp & 15);
        int k = kk * 32 + (lp >> 4) * 8 + e;
        float v = Ve[(size_t)t * T_N + k];
        __bf16 h = (__bf16)v;
        VeHi[o] = h;
        VeLo[o] = (__bf16)(v - (float)h);
        return;
    }
    __shared__ f32x4 red[16][8];
    int oid = threadIdx.x >> 3;               // 0..15
    int seg = threadIdx.x & 7;                // 0..7
    int o = blockIdx.x * 16 + oid;            // 0..8191
    int isG = o >> 12;
    int oo = o & 4095;                        // f32x4 slot in [32][128]
    int c = oo >> 7;
    int tq = oo & 127;                        // t = tq*4
    const float* src = isG ? partG : partT;
    size_t base = (size_t)c * T_N + tq * 4;
    f32x4 s = (f32x4)0.f;
#pragma unroll 4
    for (int vc = seg * 32; vc < seg * 32 + 32; ++vc)
        s += *(const f32x4*)&src[base + (size_t)vc * (C_N * T_N)];
    red[oid][seg] = s;
    __syncthreads();
    if (seg == 0) {
        f32x4 tot = red[oid][0];
#pragma unroll
        for (int k = 1; k < 8; ++k) tot += red[oid][k];
        float* dst = isG ? Gc : tmpT;
        *(f32x4*)&dst[c * T_N + tq * 4] = tot;
    }
}

// ---------------------------------------------------------------------------
// P[s][r] = sum_c Gc[c][s] * tmpT[c][r]    (K=32 tiny GEMM, fp32)
__global__ __launch_bounds__(256) void k_P2(const float* __restrict__ Gc,
                                            const float* __restrict__ tmpT,
                                            float* __restrict__ P) {
    __shared__ float Gs[32][64];
    __shared__ float Ts[32][64];
    int rbase = blockIdx.x * 64, sbase = blockIdx.y * 64;
    int tid = threadIdx.x;
    int tx = tid & 15, ty = tid >> 4;
    for (int i = tid; i < 2048; i += 256) {
        int cc = i >> 6, j = i & 63;
        Gs[cc][j] = Gc[cc * T_N + sbase + j];
        Ts[cc][j] = tmpT[cc * T_N + rbase + j];
    }
    __syncthreads();
    float acc[4][4] = {};
#pragma unroll
    for (int cc = 0; cc < 32; ++cc) {
        float a[4], b[4];
#pragma unroll
        for (int i = 0; i < 4; ++i) a[i] = Gs[cc][ty * 4 + i];
#pragma unroll
        for (int j = 0; j < 4; ++j) b[j] = Ts[cc][tx * 4 + j];
#pragma unroll
        for (int i = 0; i < 4; ++i)
#pragma unroll
            for (int j = 0; j < 4; ++j) acc[i][j] = fmaf(a[i], b[j], acc[i][j]);
    }
#pragma unroll
    for (int i = 0; i < 4; ++i) {
        f32x4 vv = {acc[i][0], acc[i][1], acc[i][2], acc[i][3]};
        *(f32x4*)&P[(size_t)(sbase + ty * 4 + i) * T_N + rbase + tx * 4] = vv;
    }
}

// ---------------------------------------------------------------------------
// Fused: per block (c, 32-wide r tile), all t (512 blocks, 2 blocks/CU):
//   S[s][r] = sigmoid(P[s][r] + be[c][s][r])   (bf16, LDS 32KB, XOR-swizzled)
//   E[t][r] = sum_s (VeHi+VeLo)[t][s] * S[s][r]  via MFMA 16x16x32 bf16
//   out[c][t][r] = softmax_t(E)
// 8 waves = 4(t) x 2(r); per wave 128t x 16r = 8x1 tiles.
__global__ __launch_bounds__(512, 4) void k_fused(const float* __restrict__ P,
                                                  const float* __restrict__ be,
                                                  const __bf16* __restrict__ VeHi,
                                                  const __bf16* __restrict__ VeLo,
                                                  float* __restrict__ out) {
    __shared__ __bf16 S[32][512];   // 32KB: S^T layout [r][s], swizzled
    const int rbase = blockIdx.x * 32;
    const int c = blockIdx.y;
    const int tid = threadIdx.x;
    const size_t cTT = (size_t)c * T_N * T_N;

    // ---- phase 1: sigmoid once per element (f32x4 loads), S^T bf16 swizzled
    {
        int r4 = (tid & 7) * 4;
        int s0 = tid >> 3;          // 0..63
        for (int i = 0; i < 8; ++i) {
            int s = i * 64 + s0;
            size_t off = (size_t)s * T_N + rbase + r4;
            f32x4 pv = *(const f32x4*)&P[off];
            f32x4 bv = *(const f32x4*)&be[cTT + off];
#pragma unroll
            for (int j = 0; j < 4; ++j) {
                float vv = pv[j] + bv[j];
                float sg = 1.0f / (1.0f + __expf(-vv));
                int rl = r4 + j;
                S[rl][s ^ ((rl & 7) << 3)] = (__bf16)sg;
            }
        }
    }
    __syncthreads();

    const int lane = tid & 63;
    const int w = tid >> 6;     // 0..7
    const int wt = w & 3;       // t-wave: 128 rows each
    const int wr = w >> 2;      // r-wave: 16 cols each
    const int lhi = lane >> 4;  // 0..3
    const int llo = lane & 15;

    const bf16x8* fragHi = (const bf16x8*)VeHi;
    const bf16x8* fragLo = (const bf16x8*)VeLo;

    f32x4 acc[8];
#pragma unroll
    for (int mi = 0; mi < 8; ++mi) acc[mi] = (f32x4)0.f;

    // ---- phase 2: K loop (s), A = packed Ve frags (L2-hot), B from LDS
    for (int k0 = 0; k0 < T_N; k0 += 32) {
        int rr = wr * 16 + llo;
        int g = (k0 >> 3) + lhi;
        bf16x8 b = *(const bf16x8*)&S[rr][(g ^ (rr & 7)) << 3];
#pragma unroll
        for (int mi = 0; mi < 8; ++mi) {
            int tile = (wt * 8 + mi) * 16 + (k0 >> 5);
            bf16x8 ah = fragHi[tile * 64 + lane];
            bf16x8 al = fragLo[tile * 64 + lane];
            acc[mi] = __builtin_amdgcn_mfma_f32_16x16x32_bf16(ah, b, acc[mi], 0, 0, 0);
            acc[mi] = __builtin_amdgcn_mfma_f32_16x16x32_bf16(al, b, acc[mi], 0, 0, 0);
        }
    }
    __syncthreads();            // done with S; reuse as reduction buffers

    float* red = (float*)&S[0][0];  // [0..127]=max, [128..255]=sum
    float gmax, gsum;

    // ---- phase 3a: column max over t
    {
        float m = -3.4e38f;
#pragma unroll
        for (int mi = 0; mi < 8; ++mi)
#pragma unroll
            for (int q = 0; q < 4; ++q) m = fmaxf(m, acc[mi][q]);
        m = fmaxf(m, __shfl_xor(m, 16));
        m = fmaxf(m, __shfl_xor(m, 32));
        if (lane < 16) red[wt * 32 + wr * 16 + llo] = m;
    }
    __syncthreads();
    {
        int col = wr * 16 + llo;
        gmax = fmaxf(fmaxf(red[col], red[32 + col]),
                     fmaxf(red[64 + col], red[96 + col]));
    }
    // ---- phase 3b: exp + column sum
    {
        float ssum = 0.f;
#pragma unroll
        for (int mi = 0; mi < 8; ++mi)
#pragma unroll
            for (int q = 0; q < 4; ++q) {
                float e = __expf(acc[mi][q] - gmax);
                acc[mi][q] = e;
                ssum += e;
            }
        ssum += __shfl_xor(ssum, 16);
        ssum += __shfl_xor(ssum, 32);
        if (lane < 16) red[128 + wt * 32 + wr * 16 + llo] = ssum;
    }
    __syncthreads();
    {
        int col = wr * 16 + llo;
        gsum = 1.0f / (red[128 + col] + red[128 + 32 + col] +
                       red[128 + 64 + col] + red[128 + 96 + col]);
    }
    // ---- phase 3c: write normalized output
    {
        int rg = rbase + wr * 16 + llo;
#pragma unroll
        for (int mi = 0; mi < 8; ++mi)
#pragma unroll
            for (int q = 0; q < 4; ++q) {
                int t = wt * 128 + mi * 16 + lhi * 4 + q;
                out[cTT + (size_t)t * T_N + rg] = acc[mi][q] * gsum;
            }
    }
}

// ---------------------------------------------------------------------------
extern "C" void kernel_launch(void* const* d_in, const int* in_sizes, int n_in,
                              void* d_out, int out_size, void* d_ws, size_t ws_size,
                              hipStream_t stream) {
    const float* x  = (const float*)d_in[0];
    const float* U1 = (const float*)d_in[1];
    const float* U2 = (const float*)d_in[2];
    const float* U3 = (const float*)d_in[3];
    const float* be = (const float*)d_in[4];
    const float* Ve = (const float*)d_in[5];
    float* out = (float*)d_out;

    float* ws    = (float*)d_ws;
    float* partT = ws;                        // 256*32*512 = 4194304 floats
    float* partG = ws + 4194304;              // 4194304
    float* P     = ws + 8388608;              // 262144
    __bf16* VeHi = (__bf16*)(ws + 8650752);   // 262144 bf16 (131072 slots)
    __bf16* VeLo = (__bf16*)(ws + 8781824);   // 262144 bf16
    float* tmpT  = ws + 8912896;              // 16384
    float* Gc    = ws + 8929280;              // 16384
    // total ~8945664 floats ~= 35.8 MB

    k_rt    <<<256, 256, 0, stream>>>(x, U1, U2, U3, partT, partG);
    k_redpre<<<512 + 2048, 128, 0, stream>>>(partT, partG, tmpT, Gc, Ve, VeHi, VeLo);
    k_P2    <<<dim3(8, 8), 256, 0, stream>>>(Gc, tmpT, P);
    k_fused <<<dim3(16, C_N), 512, 0, stream>>>(P, be, VeHi, VeLo, out);
}

// Round 16
// 119.107 us; speedup vs baseline: 2.9659x; 1.0063x over previous
//
#include <hip/hip_runtime.h>

#define V_N 4096
#define C_N 32
#define T_N 512

typedef float f32x4 __attribute__((ext_vector_type(4)));
typedef __bf16 bf16x8 __attribute__((ext_vector_type(8)));

__device__ inline f32x4 fma4(f32x4 a, float b, f32x4 c) {
    f32x4 r;
    r.x = fmaf(a.x, b, c.x); r.y = fmaf(a.y, b, c.y);
    r.z = fmaf(a.z, b, c.z); r.w = fmaf(a.w, b, c.w);
    return r;
}

// ---------------------------------------------------------------------------
// Streaming x-pass, t-half blocks (register demand ~110 < any observed
// compiler VGPR target -> spill-proof; R12/R13/R14 spilled at demand ~200).
// Block (vc, half) = 16 v-planes x 256-t half; wave w owns c = w*8+i.
// Per plane: 8 x 1KB contiguous half-row wave-loads feeding FMAs directly.
// No branch, no staging arrays, launch_bounds(256,1) — the proven-safe shape.
// 512 blocks -> 2+ blocks/CU hide the 16 per-plane barriers.
//   partT[vc][c][t] = sum_{vi} x[v,c,t]*U1[v]
//   partG[vc][c][t] = sum_{vi} rhs[v,t]*U2[c,v],  rhs = sum_c x*U3[c]
__global__ __launch_bounds__(256, 1) void k_rt(const float* __restrict__ x,
                                               const float* __restrict__ U1,
                                               const float* __restrict__ U2,
                                               const float* __restrict__ U3,
                                               float* __restrict__ partT,
                                               float* __restrict__ partG) {
    const int vc = blockIdx.x >> 1;       // 0..255, 16 v each
    const int half = blockIdx.x & 1;      // t-half
    const int tid = threadIdx.x;
    const int w = tid >> 6;               // wave 0..3
    const int l = tid & 63;               // lane
    const int v0 = vc * 16;

    __shared__ f32x4 lsum[2][4][64];      // 8KB: [buf][wave][lane]

    float u3loc[8];
#pragma unroll
    for (int i = 0; i < 8; ++i) u3loc[i] = U3[w * 8 + i];

    f32x4 accT[8], gacc[8];
#pragma unroll
    for (int i = 0; i < 8; ++i) { accT[i] = (f32x4)0.f; gacc[i] = (f32x4)0.f; }

    const float* xbase = x + (size_t)v0 * (C_N * T_N) + half * 256 + l * 4;

#pragma unroll 1
    for (int vi = 0; vi < 16; ++vi) {
        const float* xp = xbase + (size_t)vi * (C_N * T_N);
        float u1 = U1[v0 + vi];
        int buf = vi & 1;
        f32x4 racc = (f32x4)0.f;
#pragma unroll
        for (int i = 0; i < 8; ++i) {
            f32x4 xv = *(const f32x4*)(xp + (size_t)(w * 8 + i) * T_N);
            accT[i] = fma4(xv, u1, accT[i]);
            racc = fma4(xv, u3loc[i], racc);
        }
        lsum[buf][w][l] = racc;
        __syncthreads();
        f32x4 rhs = (lsum[buf][0][l] + lsum[buf][1][l]) +
                    (lsum[buf][2][l] + lsum[buf][3][l]);
#pragma unroll
        for (int i = 0; i < 8; ++i)
            gacc[i] = fma4(rhs, U2[(size_t)(w * 8 + i) * V_N + v0 + vi], gacc[i]);
    }

    const size_t pbase = (size_t)vc * (C_N * T_N) + half * 256 + l * 4;
#pragma unroll
    for (int i = 0; i < 8; ++i) {
        size_t off = pbase + (size_t)(w * 8 + i) * T_N;
        *(f32x4*)&partT[off] = accT[i];
        *(f32x4*)&partG[off] = gacc[i];
    }
}

// ---------------------------------------------------------------------------
// Blocks 0..511: fixed-order reduce of 256 chunk-partials -> tmpT, Gc.
//   lane map: oid = tid&15 (fast) so same-seg lanes read 256B contiguous runs.
// Blocks 512..2559: Ve hi/lo split in MFMA A-fragment order (low-VGPR kernel,
// branch is safe here).
__global__ __launch_bounds__(128) void k_redpre(const float* __restrict__ partT,
                                                const float* __restrict__ partG,
                                                float* __restrict__ tmpT,
                                                float* __restrict__ Gc,
                                                const float* __restrict__ Ve,
                                                __bf16* __restrict__ VeHi,
                                                __bf16* __restrict__ VeLo) {
    if (blockIdx.x >= 512) {
        // Ve split: o -> tile, lane lp, elem e:
        //   t=(tile>>4)*16+(lp&15), k=(tile&15)*32+(lp>>4)*8+e
        int o = (blockIdx.x - 512) * 128 + threadIdx.x;   // 0..262143
        int e = o & 7, lp = (o >> 3) & 63, tile = o >> 9;
        int kk = tile & 15, tt = tile >> 4;
        int t = tt * 16 + (lp & 15);
        int k = kk * 32 + (lp >> 4) * 8 + e;
        float v = Ve[(size_t)t * T_N + k];
        __bf16 h = (__bf16)v;
        VeHi[o] = h;
        VeLo[o] = (__bf16)(v - (float)h);
        return;
    }
    __shared__ f32x4 red[16][8];
    int oid = threadIdx.x & 15;               // 0..15 (fast -> contiguous)
    int seg = threadIdx.x >> 4;               // 0..7
    int o = blockIdx.x * 16 + oid;            // 0..8191
    int isG = o >> 12;
    int oo = o & 4095;                        // f32x4 slot in [32][128]
    int c = oo >> 7;
    int tq = oo & 127;                        // t = tq*4
    const float* src = isG ? partG : partT;
    size_t base = (size_t)c * T_N + tq * 4;
    f32x4 s = (f32x4)0.f;
#pragma unroll 4
    for (int vc = seg * 32; vc < seg * 32 + 32; ++vc)
        s += *(const f32x4*)&src[base + (size_t)vc * (C_N * T_N)];
    red[oid][seg] = s;
    __syncthreads();
    if (seg == 0) {
        f32x4 tot = red[oid][0];
#pragma unroll
        for (int k = 1; k < 8; ++k) tot += red[oid][k];
        float* dst = isG ? Gc : tmpT;
        *(f32x4*)&dst[c * T_N + tq * 4] = tot;
    }
}

// ---------------------------------------------------------------------------
// P[s][r] = sum_c Gc[c][s] * tmpT[c][r]    (K=32 tiny GEMM, fp32)
__global__ __launch_bounds__(256) void k_P2(const float* __restrict__ Gc,
                                            const float* __restrict__ tmpT,
                                            float* __restrict__ P) {
    __shared__ float Gs[32][64];
    __shared__ float Ts[32][64];
    int rbase = blockIdx.x * 64, sbase = blockIdx.y * 64;
    int tid = threadIdx.x;
    int tx = tid & 15, ty = tid >> 4;
    for (int i = tid; i < 2048; i += 256) {
        int cc = i >> 6, j = i & 63;
        Gs[cc][j] = Gc[cc * T_N + sbase + j];
        Ts[cc][j] = tmpT[cc * T_N + rbase + j];
    }
    __syncthreads();
    float acc[4][4] = {};
#pragma unroll
    for (int cc = 0; cc < 32; ++cc) {
        float a[4], b[4];
#pragma unroll
        for (int i = 0; i < 4; ++i) a[i] = Gs[cc][ty * 4 + i];
#pragma unroll
        for (int j = 0; j < 4; ++j) b[j] = Ts[cc][tx * 4 + j];
#pragma unroll
        for (int i = 0; i < 4; ++i)
#pragma unroll
            for (int j = 0; j < 4; ++j) acc[i][j] = fmaf(a[i], b[j], acc[i][j]);
    }
#pragma unroll
    for (int i = 0; i < 4; ++i) {
        f32x4 vv = {acc[i][0], acc[i][1], acc[i][2], acc[i][3]};
        *(f32x4*)&P[(size_t)(sbase + ty * 4 + i) * T_N + rbase + tx * 4] = vv;
    }
}

// ---------------------------------------------------------------------------
// Fused: per block (c, 32-wide r tile), all t (512 blocks, 2 blocks/CU):
//   S[s][r] = sigmoid(P[s][r] + be[c][s][r])   (bf16, LDS 32KB, XOR-swizzled)
//   E[t][r] = sum_s (VeHi+VeLo)[t][s] * S[s][r]  via MFMA 16x16x32 bf16
//   out[c][t][r] = softmax_t(E)
// 8 waves = 4(t) x 2(r); per wave 128t x 16r = 8x1 tiles.
__global__ __launch_bounds__(512, 4) void k_fused(const float* __restrict__ P,
                                                  const float* __restrict__ be,
                                                  const __bf16* __restrict__ VeHi,
                                                  const __bf16* __restrict__ VeLo,
                                                  float* __restrict__ out) {
    __shared__ __bf16 S[32][512];   // 32KB: S^T layout [r][s], swizzled
    const int rbase = blockIdx.x * 32;
    const int c = blockIdx.y;
    const int tid = threadIdx.x;
    const size_t cTT = (size_t)c * T_N * T_N;

    // ---- phase 1: sigmoid once per element (f32x4 loads), S^T bf16 swizzled
    {
        int r4 = (tid & 7) * 4;
        int s0 = tid >> 3;          // 0..63
        for (int i = 0; i < 8; ++i) {
            int s = i * 64 + s0;
            size_t off = (size_t)s * T_N + rbase + r4;
            f32x4 pv = *(const f32x4*)&P[off];
            f32x4 bv = *(const f32x4*)&be[cTT + off];
#pragma unroll
            for (int j = 0; j < 4; ++j) {
                float vv = pv[j] + bv[j];
                float sg = 1.0f / (1.0f + __expf(-vv));
                int rl = r4 + j;
                S[rl][s ^ ((rl & 7) << 3)] = (__bf16)sg;
            }
        }
    }
    __syncthreads();

    const int lane = tid & 63;
    const int w = tid >> 6;     // 0..7
    const int wt = w & 3;       // t-wave: 128 rows each
    const int wr = w >> 2;      // r-wave: 16 cols each
    const int lhi = lane >> 4;  // 0..3
    const int llo = lane & 15;

    const bf16x8* fragHi = (const bf16x8*)VeHi;
    const bf16x8* fragLo = (const bf16x8*)VeLo;

    f32x4 acc[8];
#pragma unroll
    for (int mi = 0; mi < 8; ++mi) acc[mi] = (f32x4)0.f;

    // ---- phase 2: K loop (s), A = packed Ve frags (L2-hot), B from LDS
    for (int k0 = 0; k0 < T_N; k0 += 32) {
        int rr = wr * 16 + llo;
        int g = (k0 >> 3) + lhi;
        bf16x8 b = *(const bf16x8*)&S[rr][(g ^ (rr & 7)) << 3];
#pragma unroll
        for (int mi = 0; mi < 8; ++mi) {
            int tile = (wt * 8 + mi) * 16 + (k0 >> 5);
            bf16x8 ah = fragHi[tile * 64 + lane];
            bf16x8 al = fragLo[tile * 64 + lane];
            acc[mi] = __builtin_amdgcn_mfma_f32_16x16x32_bf16(ah, b, acc[mi], 0, 0, 0);
            acc[mi] = __builtin_amdgcn_mfma_f32_16x16x32_bf16(al, b, acc[mi], 0, 0, 0);
        }
    }
    __syncthreads();            // done with S; reuse as reduction buffers

    float* red = (float*)&S[0][0];  // [0..127]=max, [128..255]=sum
    float gmax, gsum;

    // ---- phase 3a: column max over t
    {
        float m = -3.4e38f;
#pragma unroll
        for (int mi = 0; mi < 8; ++mi)
#pragma unroll
            for (int q = 0; q < 4; ++q) m = fmaxf(m, acc[mi][q]);
        m = fmaxf(m, __shfl_xor(m, 16));
        m = fmaxf(m, __shfl_xor(m, 32));
        if (lane < 16) red[wt * 32 + wr * 16 + llo] = m;
    }
    __syncthreads();
    {
        int col = wr * 16 + llo;
        gmax = fmaxf(fmaxf(red[col], red[32 + col]),
                     fmaxf(red[64 + col], red[96 + col]));
    }
    // ---- phase 3b: exp + column sum
    {
        float ssum = 0.f;
#pragma unroll
        for (int mi = 0; mi < 8; ++mi)
#pragma unroll
            for (int q = 0; q < 4; ++q) {
                float e = __expf(acc[mi][q] - gmax);
                acc[mi][q] = e;
                ssum += e;
            }
        ssum += __shfl_xor(ssum, 16);
        ssum += __shfl_xor(ssum, 32);
        if (lane < 16) red[128 + wt * 32 + wr * 16 + llo] = ssum;
    }
    __syncthreads();
    {
        int col = wr * 16 + llo;
        gsum = 1.0f / (red[128 + col] + red[128 + 32 + col] +
                       red[128 + 64 + col] + red[128 + 96 + col]);
    }
    // ---- phase 3c: write normalized output
    {
        int rg = rbase + wr * 16 + llo;
#pragma unroll
        for (int mi = 0; mi < 8; ++mi)
#pragma unroll
            for (int q = 0; q < 4; ++q) {
                int t = wt * 128 + mi * 16 + lhi * 4 + q;
                out[cTT + (size_t)t * T_N + rg] = acc[mi][q] * gsum;
            }
    }
}

// ---------------------------------------------------------------------------
extern "C" void kernel_launch(void* const* d_in, const int* in_sizes, int n_in,
                              void* d_out, int out_size, void* d_ws, size_t ws_size,
                              hipStream_t stream) {
    const float* x  = (const float*)d_in[0];
    const float* U1 = (const float*)d_in[1];
    const float* U2 = (const float*)d_in[2];
    const float* U3 = (const float*)d_in[3];
    const float* be = (const float*)d_in[4];
    const float* Ve = (const float*)d_in[5];
    float* out = (float*)d_out;

    float* ws    = (float*)d_ws;
    float* partT = ws;                        // 256*32*512 = 4194304 floats
    float* partG = ws + 4194304;              // 4194304
    float* P     = ws + 8388608;              // 262144
    __bf16* VeHi = (__bf16*)(ws + 8650752);   // 262144 bf16 (131072 slots)
    __bf16* VeLo = (__bf16*)(ws + 8781824);   // 262144 bf16
    float* tmpT  = ws + 8912896;              // 16384
    float* Gc    = ws + 8929280;              // 16384
    // total ~8945664 floats ~= 35.8 MB

    k_rt    <<<512, 256, 0, stream>>>(x, U1, U2, U3, partT, partG);
    k_redpre<<<512 + 2048, 128, 0, stream>>>(partT, partG, tmpT, Gc, Ve, VeHi, VeLo);
    k_P2    <<<dim3(8, 8), 256, 0, stream>>>(Gc, tmpT, P);
    k_fused <<<dim3(16, C_N), 512, 0, stream>>>(P, be, VeHi, VeLo, out);
}

// Round 17
// 116.891 us; speedup vs baseline: 3.0221x; 1.0190x over previous
//
#include <hip/hip_runtime.h>

#define V_N 4096
#define C_N 32
#define T_N 512

typedef float f32x4 __attribute__((ext_vector_type(4)));
typedef __bf16 bf16x4 __attribute__((ext_vector_type(4)));
typedef __bf16 bf16x8 __attribute__((ext_vector_type(8)));

__device__ inline f32x4 fma4(f32x4 a, float b, f32x4 c) {
    f32x4 r;
    r.x = fmaf(a.x, b, c.x); r.y = fmaf(a.y, b, c.y);
    r.z = fmaf(a.z, b, c.z); r.w = fmaf(a.w, b, c.w);
    return r;
}

// ---------------------------------------------------------------------------
// Streaming x-pass with global_load_lds pipeline (T3/T4: counted vmcnt, no
// per-plane memory drain). Block (vc, half) = 16 v-planes x 256-t half.
// Wave w stages AND reads only rows c = w*8..w*8+7 -> xbuf needs no barrier;
// only the lsum combine barriers (lgkmcnt(0) + raw s_barrier, vmcnt unfenced
// so next plane's stage loads stay in flight). U1/U2/U3 pre-staged to LDS so
// loop VMEM = exactly the 8 stage loads (precise vmcnt counting).
//   partT[vc][c][t] = sum_{vi} x[v,c,t]*U1[v]
//   partG[vc][c][t] = sum_{vi} rhs[v,t]*U2[c,v],  rhs = sum_c x*U3[c]
__global__ __launch_bounds__(256, 1) void k_rt(const float* __restrict__ x,
                                               const float* __restrict__ U1,
                                               const float* __restrict__ U2,
                                               const float* __restrict__ U3,
                                               float* __restrict__ partT,
                                               float* __restrict__ partG) {
    __shared__ float xbuf[2][32][256];    // 64KB double-buffered plane
    __shared__ f32x4 lsum[2][4][64];      // 8KB cross-wave rhs combine
    __shared__ float u2s[32][16];         // 2KB U2 slice [c][vi]
    __shared__ float u1s[16];
    __shared__ float u3s[32];

    const int vc = blockIdx.x >> 1;       // 0..255, 16 v each
    const int half = blockIdx.x & 1;      // t-half
    const int tid = threadIdx.x;
    const int w = tid >> 6;               // wave 0..3
    const int l = tid & 63;               // lane
    const int v0 = vc * 16;

    // ---- prologue: stage U-vectors to LDS (full syncthreads OK here)
    if (tid < 16) u1s[tid] = U1[v0 + tid];
    if (tid < 32) u3s[tid] = U3[tid];
    {
        int c = tid >> 3, e = tid & 7;    // 256 threads x 2 elems
        u2s[c][e] = U2[(size_t)c * V_N + v0 + e];
        u2s[c][e + 8] = U2[(size_t)c * V_N + v0 + e + 8];
    }
    __syncthreads();

    float u3loc[8];
#pragma unroll
    for (int i = 0; i < 8; ++i) u3loc[i] = u3s[w * 8 + i];

    f32x4 accT[8], gacc[8];
#pragma unroll
    for (int i = 0; i < 8; ++i) { accT[i] = (f32x4)0.f; gacc[i] = (f32x4)0.f; }

    const float* xbase = x + (size_t)v0 * (C_N * T_N) + half * 256 + l * 4;

#define STAGE(vi) {                                                          \
    const float* xp_ = xbase + (size_t)(vi) * (C_N * T_N);                   \
    _Pragma("unroll")                                                        \
    for (int i_ = 0; i_ < 8; ++i_) {                                         \
        __builtin_amdgcn_global_load_lds(                                    \
            (const __attribute__((address_space(1))) void*)                  \
                (xp_ + (size_t)(w * 8 + i_) * T_N),                          \
            (__attribute__((address_space(3))) void*)                        \
                &xbuf[(vi) & 1][w * 8 + i_][0],                              \
            16, 0, 0);                                                       \
    } }

    STAGE(0);
#pragma unroll 1
    for (int vi = 0; vi < 16; ++vi) {
        const int buf = vi & 1;
        if (vi + 1 < 16) {
            STAGE(vi + 1);                               // issue next plane
            asm volatile("s_waitcnt vmcnt(8)" ::: "memory");  // this plane done
        } else {
            asm volatile("s_waitcnt vmcnt(0)" ::: "memory");
        }
        __builtin_amdgcn_sched_barrier(0);
        float u1 = u1s[vi];
        f32x4 racc = (f32x4)0.f;
#pragma unroll
        for (int i = 0; i < 8; ++i) {
            f32x4 xv = *(const f32x4*)&xbuf[buf][w * 8 + i][l * 4];
            accT[i] = fma4(xv, u1, accT[i]);
            racc = fma4(xv, u3loc[i], racc);
        }
        lsum[buf][w][l] = racc;
        asm volatile("s_waitcnt lgkmcnt(0)" ::: "memory");
        __builtin_amdgcn_sched_barrier(0);
        __builtin_amdgcn_s_barrier();                    // raw: vmcnt unfenced
        f32x4 rhs = (lsum[buf][0][l] + lsum[buf][1][l]) +
                    (lsum[buf][2][l] + lsum[buf][3][l]);
#pragma unroll
        for (int i = 0; i < 8; ++i)
            gacc[i] = fma4(rhs, u2s[w * 8 + i][vi], gacc[i]);
    }
#undef STAGE

    const size_t pbase = (size_t)vc * (C_N * T_N) + half * 256 + l * 4;
#pragma unroll
    for (int i = 0; i < 8; ++i) {
        size_t off = pbase + (size_t)(w * 8 + i) * T_N;
        *(f32x4*)&partT[off] = accT[i];
        *(f32x4*)&partG[off] = gacc[i];
    }
}

// ---------------------------------------------------------------------------
// Blocks 0..511: fixed-order reduce of 256 chunk-partials -> tmpT, Gc.
// Blocks 512..1023: Ve hi/lo split, x4 vectorized (f32x4 load, bf16x4 store),
// MFMA A-fragment order.
__global__ __launch_bounds__(128) void k_redpre(const float* __restrict__ partT,
                                                const float* __restrict__ partG,
                                                float* __restrict__ tmpT,
                                                float* __restrict__ Gc,
                                                const float* __restrict__ Ve,
                                                __bf16* __restrict__ VeHi,
                                                __bf16* __restrict__ VeLo) {
    if (blockIdx.x >= 512) {
        // o -> tile, lane lp, elem e: t=(tile>>4)*16+(lp&15),
        // k=(tile&15)*32+(lp>>4)*8+e ; 4 consecutive e = 4 consecutive k.
        int o = ((blockIdx.x - 512) * 128 + threadIdx.x) * 4;  // 0..262140
        int e0 = o & 7, lp = (o >> 3) & 63, tile = o >> 9;
        int kk = tile & 15, tt = tile >> 4;
        int t = tt * 16 + (lp & 15);
        int k = kk * 32 + (lp >> 4) * 8 + e0;
        f32x4 v = *(const f32x4*)&Ve[(size_t)t * T_N + k];
        bf16x4 h, lo;
#pragma unroll
        for (int j = 0; j < 4; ++j) {
            h[j] = (__bf16)v[j];
            lo[j] = (__bf16)(v[j] - (float)h[j]);
        }
        *(bf16x4*)&VeHi[o] = h;
        *(bf16x4*)&VeLo[o] = lo;
        return;
    }
    __shared__ f32x4 red[16][8];
    int oid = threadIdx.x & 15;               // 0..15 (fast -> contiguous)
    int seg = threadIdx.x >> 4;               // 0..7
    int o = blockIdx.x * 16 + oid;            // 0..8191
    int isG = o >> 12;
    int oo = o & 4095;                        // f32x4 slot in [32][128]
    int c = oo >> 7;
    int tq = oo & 127;                        // t = tq*4
    const float* src = isG ? partG : partT;
    size_t base = (size_t)c * T_N + tq * 4;
    f32x4 s = (f32x4)0.f;
#pragma unroll 4
    for (int vc = seg * 32; vc < seg * 32 + 32; ++vc)
        s += *(const f32x4*)&src[base + (size_t)vc * (C_N * T_N)];
    red[oid][seg] = s;
    __syncthreads();
    if (seg == 0) {
        f32x4 tot = red[oid][0];
#pragma unroll
        for (int k = 1; k < 8; ++k) tot += red[oid][k];
        float* dst = isG ? Gc : tmpT;
        *(f32x4*)&dst[c * T_N + tq * 4] = tot;
    }
}

// ---------------------------------------------------------------------------
// P[s][r] = sum_c Gc[c][s] * tmpT[c][r]    (K=32 tiny GEMM, fp32)
__global__ __launch_bounds__(256) void k_P2(const float* __restrict__ Gc,
                                            const float* __restrict__ tmpT,
                                            float* __restrict__ P) {
    __shared__ float Gs[32][64];
    __shared__ float Ts[32][64];
    int rbase = blockIdx.x * 64, sbase = blockIdx.y * 64;
    int tid = threadIdx.x;
    int tx = tid & 15, ty = tid >> 4;
    for (int i = tid; i < 2048; i += 256) {
        int cc = i >> 6, j = i & 63;
        Gs[cc][j] = Gc[cc * T_N + sbase + j];
        Ts[cc][j] = tmpT[cc * T_N + rbase + j];
    }
    __syncthreads();
    float acc[4][4] = {};
#pragma unroll
    for (int cc = 0; cc < 32; ++cc) {
        float a[4], b[4];
#pragma unroll
        for (int i = 0; i < 4; ++i) a[i] = Gs[cc][ty * 4 + i];
#pragma unroll
        for (int j = 0; j < 4; ++j) b[j] = Ts[cc][tx * 4 + j];
#pragma unroll
        for (int i = 0; i < 4; ++i)
#pragma unroll
            for (int j = 0; j < 4; ++j) acc[i][j] = fmaf(a[i], b[j], acc[i][j]);
    }
#pragma unroll
    for (int i = 0; i < 4; ++i) {
        f32x4 vv = {acc[i][0], acc[i][1], acc[i][2], acc[i][3]};
        *(f32x4*)&P[(size_t)(sbase + ty * 4 + i) * T_N + rbase + tx * 4] = vv;
    }
}

// ---------------------------------------------------------------------------
// Fused: per block (c, 32-wide r tile), all t (512 blocks, 2 blocks/CU):
//   S[s][r] = sigmoid(P[s][r] + be[c][s][r])   (bf16, LDS 32KB, XOR-swizzled)
//   E[t][r] = sum_s (VeHi+VeLo)[t][s] * S[s][r]  via MFMA 16x16x32 bf16
//   out[c][t][r] = softmax_t(E)
// 8 waves = 4(t) x 2(r); per wave 128t x 16r = 8x1 tiles.
__global__ __launch_bounds__(512, 4) void k_fused(const float* __restrict__ P,
                                                  const float* __restrict__ be,
                                                  const __bf16* __restrict__ VeHi,
                                                  const __bf16* __restrict__ VeLo,
                                                  float* __restrict__ out) {
    __shared__ __bf16 S[32][512];   // 32KB: S^T layout [r][s], swizzled
    const int rbase = blockIdx.x * 32;
    const int c = blockIdx.y;
    const int tid = threadIdx.x;
    const size_t cTT = (size_t)c * T_N * T_N;

    // ---- phase 1: sigmoid once per element (f32x4 loads), S^T bf16 swizzled
    {
        int r4 = (tid & 7) * 4;
        int s0 = tid >> 3;          // 0..63
        for (int i = 0; i < 8; ++i) {
            int s = i * 64 + s0;
            size_t off = (size_t)s * T_N + rbase + r4;
            f32x4 pv = *(const f32x4*)&P[off];
            f32x4 bv = *(const f32x4*)&be[cTT + off];
#pragma unroll
            for (int j = 0; j < 4; ++j) {
                float vv = pv[j] + bv[j];
                float sg = 1.0f / (1.0f + __expf(-vv));
                int rl = r4 + j;
                S[rl][s ^ ((rl & 7) << 3)] = (__bf16)sg;
            }
        }
    }
    __syncthreads();

    const int lane = tid & 63;
    const int w = tid >> 6;     // 0..7
    const int wt = w & 3;       // t-wave: 128 rows each
    const int wr = w >> 2;      // r-wave: 16 cols each
    const int lhi = lane >> 4;  // 0..3
    const int llo = lane & 15;

    const bf16x8* fragHi = (const bf16x8*)VeHi;
    const bf16x8* fragLo = (const bf16x8*)VeLo;

    f32x4 acc[8];
#pragma unroll
    for (int mi = 0; mi < 8; ++mi) acc[mi] = (f32x4)0.f;

    // ---- phase 2: K loop (s), A = packed Ve frags (L2-hot), B from LDS
    for (int k0 = 0; k0 < T_N; k0 += 32) {
        int rr = wr * 16 + llo;
        int g = (k0 >> 3) + lhi;
        bf16x8 b = *(const bf16x8*)&S[rr][(g ^ (rr & 7)) << 3];
#pragma unroll
        for (int mi = 0; mi < 8; ++mi) {
            int tile = (wt * 8 + mi) * 16 + (k0 >> 5);
            bf16x8 ah = fragHi[tile * 64 + lane];
            bf16x8 al = fragLo[tile * 64 + lane];
            acc[mi] = __builtin_amdgcn_mfma_f32_16x16x32_bf16(ah, b, acc[mi], 0, 0, 0);
            acc[mi] = __builtin_amdgcn_mfma_f32_16x16x32_bf16(al, b, acc[mi], 0, 0, 0);
        }
    }
    __syncthreads();            // done with S; reuse as reduction buffers

    float* red = (float*)&S[0][0];  // [0..127]=max, [128..255]=sum
    float gmax, gsum;

    // ---- phase 3a: column max over t
    {
        float m = -3.4e38f;
#pragma unroll
        for (int mi = 0; mi < 8; ++mi)
#pragma unroll
            for (int q = 0; q < 4; ++q) m = fmaxf(m, acc[mi][q]);
        m = fmaxf(m, __shfl_xor(m, 16));
        m = fmaxf(m, __shfl_xor(m, 32));
        if (lane < 16) red[wt * 32 + wr * 16 + llo] = m;
    }
    __syncthreads();
    {
        int col = wr * 16 + llo;
        gmax = fmaxf(fmaxf(red[col], red[32 + col]),
                     fmaxf(red[64 + col], red[96 + col]));
    }
    // ---- phase 3b: exp + column sum
    {
        float ssum = 0.f;
#pragma unroll
        for (int mi = 0; mi < 8; ++mi)
#pragma unroll
            for (int q = 0; q < 4; ++q) {
                float e = __expf(acc[mi][q] - gmax);
                acc[mi][q] = e;
                ssum += e;
            }
        ssum += __shfl_xor(ssum, 16);
        ssum += __shfl_xor(ssum, 32);
        if (lane < 16) red[128 + wt * 32 + wr * 16 + llo] = ssum;
    }
    __syncthreads();
    {
        int col = wr * 16 + llo;
        gsum = 1.0f / (red[128 + col] + red[128 + 32 + col] +
                       red[128 + 64 + col] + red[128 + 96 + col]);
    }
    // ---- phase 3c: write normalized output
    {
        int rg = rbase + wr * 16 + llo;
#pragma unroll
        for (int mi = 0; mi < 8; ++mi)
#pragma unroll
            for (int q = 0; q < 4; ++q) {
                int t = wt * 128 + mi * 16 + lhi * 4 + q;
                out[cTT + (size_t)t * T_N + rg] = acc[mi][q] * gsum;
            }
    }
}

// ---------------------------------------------------------------------------
extern "C" void kernel_launch(void* const* d_in, const int* in_sizes, int n_in,
                              void* d_out, int out_size, void* d_ws, size_t ws_size,
                              hipStream_t stream) {
    const float* x  = (const float*)d_in[0];
    const float* U1 = (const float*)d_in[1];
    const float* U2 = (const float*)d_in[2];
    const float* U3 = (const float*)d_in[3];
    const float* be = (const float*)d_in[4];
    const float* Ve = (const float*)d_in[5];
    float* out = (float*)d_out;

    float* ws    = (float*)d_ws;
    float* partT = ws;                        // 256*32*512 = 4194304 floats
    float* partG = ws + 4194304;              // 4194304
    float* P     = ws + 8388608;              // 262144
    __bf16* VeHi = (__bf16*)(ws + 8650752);   // 262144 bf16 (131072 slots)
    __bf16* VeLo = (__bf16*)(ws + 8781824);   // 262144 bf16
    float* tmpT  = ws + 8912896;              // 16384
    float* Gc    = ws + 8929280;              // 16384
    // total ~8945664 floats ~= 35.8 MB

    k_rt    <<<512, 256, 0, stream>>>(x, U1, U2, U3, partT, partG);
    k_redpre<<<512 + 512, 128, 0, stream>>>(partT, partG, tmpT, Gc, Ve, VeHi, VeLo);
    k_P2    <<<dim3(8, 8), 256, 0, stream>>>(Gc, tmpT, P);
    k_fused <<<dim3(16, C_N), 512, 0, stream>>>(P, be, VeHi, VeLo, out);
}

// Round 18
// 104.682 us; speedup vs baseline: 3.3746x; 1.1166x over previous
//
#include <hip/hip_runtime.h>

#define V_N 4096
#define C_N 32
#define T_N 512

typedef float f32x4 __attribute__((ext_vector_type(4)));
typedef __bf16 bf16x4 __attribute__((ext_vector_type(4)));
typedef __bf16 bf16x8 __attribute__((ext_vector_type(8)));

__device__ inline f32x4 fma4(f32x4 a, float b, f32x4 c) {
    f32x4 r;
    r.x = fmaf(a.x, b, c.x); r.y = fmaf(a.y, b, c.y);
    r.z = fmaf(a.z, b, c.z); r.w = fmaf(a.w, b, c.w);
    return r;
}

// ---------------------------------------------------------------------------
// Streaming x-pass with global_load_lds pipeline (frozen — R17 verified).
// Block (vc, half) = 16 v-planes x 256-t half. Wave w stages AND reads only
// rows c = w*8..w*8+7 -> xbuf needs no barrier; only the lsum combine
// barriers (lgkmcnt(0) + raw s_barrier, vmcnt unfenced).
//   partT[vc][c][t] = sum_{vi} x[v,c,t]*U1[v]
//   partG[vc][c][t] = sum_{vi} rhs[v,t]*U2[c,v],  rhs = sum_c x*U3[c]
__global__ __launch_bounds__(256, 1) void k_rt(const float* __restrict__ x,
                                               const float* __restrict__ U1,
                                               const float* __restrict__ U2,
                                               const float* __restrict__ U3,
                                               float* __restrict__ partT,
                                               float* __restrict__ partG) {
    __shared__ float xbuf[2][32][256];    // 64KB double-buffered plane
    __shared__ f32x4 lsum[2][4][64];      // 8KB cross-wave rhs combine
    __shared__ float u2s[32][16];         // 2KB U2 slice [c][vi]
    __shared__ float u1s[16];
    __shared__ float u3s[32];

    const int vc = blockIdx.x >> 1;       // 0..255, 16 v each
    const int half = blockIdx.x & 1;      // t-half
    const int tid = threadIdx.x;
    const int w = tid >> 6;               // wave 0..3
    const int l = tid & 63;               // lane
    const int v0 = vc * 16;

    if (tid < 16) u1s[tid] = U1[v0 + tid];
    if (tid < 32) u3s[tid] = U3[tid];
    {
        int c = tid >> 3, e = tid & 7;
        u2s[c][e] = U2[(size_t)c * V_N + v0 + e];
        u2s[c][e + 8] = U2[(size_t)c * V_N + v0 + e + 8];
    }
    __syncthreads();

    float u3loc[8];
#pragma unroll
    for (int i = 0; i < 8; ++i) u3loc[i] = u3s[w * 8 + i];

    f32x4 accT[8], gacc[8];
#pragma unroll
    for (int i = 0; i < 8; ++i) { accT[i] = (f32x4)0.f; gacc[i] = (f32x4)0.f; }

    const float* xbase = x + (size_t)v0 * (C_N * T_N) + half * 256 + l * 4;

#define STAGE(vi) {                                                          \
    const float* xp_ = xbase + (size_t)(vi) * (C_N * T_N);                   \
    _Pragma("unroll")                                                        \
    for (int i_ = 0; i_ < 8; ++i_) {                                         \
        __builtin_amdgcn_global_load_lds(                                    \
            (const __attribute__((address_space(1))) void*)                  \
                (xp_ + (size_t)(w * 8 + i_) * T_N),                          \
            (__attribute__((address_space(3))) void*)                        \
                &xbuf[(vi) & 1][w * 8 + i_][0],                              \
            16, 0, 0);                                                       \
    } }

    STAGE(0);
#pragma unroll 1
    for (int vi = 0; vi < 16; ++vi) {
        const int buf = vi & 1;
        if (vi + 1 < 16) {
            STAGE(vi + 1);
            asm volatile("s_waitcnt vmcnt(8)" ::: "memory");
        } else {
            asm volatile("s_waitcnt vmcnt(0)" ::: "memory");
        }
        __builtin_amdgcn_sched_barrier(0);
        float u1 = u1s[vi];
        f32x4 racc = (f32x4)0.f;
#pragma unroll
        for (int i = 0; i < 8; ++i) {
            f32x4 xv = *(const f32x4*)&xbuf[buf][w * 8 + i][l * 4];
            accT[i] = fma4(xv, u1, accT[i]);
            racc = fma4(xv, u3loc[i], racc);
        }
        lsum[buf][w][l] = racc;
        asm volatile("s_waitcnt lgkmcnt(0)" ::: "memory");
        __builtin_amdgcn_sched_barrier(0);
        __builtin_amdgcn_s_barrier();                    // raw: vmcnt unfenced
        f32x4 rhs = (lsum[buf][0][l] + lsum[buf][1][l]) +
                    (lsum[buf][2][l] + lsum[buf][3][l]);
#pragma unroll
        for (int i = 0; i < 8; ++i)
            gacc[i] = fma4(rhs, u2s[w * 8 + i][vi], gacc[i]);
    }
#undef STAGE

    const size_t pbase = (size_t)vc * (C_N * T_N) + half * 256 + l * 4;
#pragma unroll
    for (int i = 0; i < 8; ++i) {
        size_t off = pbase + (size_t)(w * 8 + i) * T_N;
        *(f32x4*)&partT[off] = accT[i];
        *(f32x4*)&partG[off] = gacc[i];
    }
}

// ---------------------------------------------------------------------------
// Blocks 0..511: fixed-order reduce of 256 chunk-partials -> tmpT, Gc.
// Blocks 512..1023: Ve hi/lo split, x4 vectorized, MFMA A-fragment order.
__global__ __launch_bounds__(128) void k_redpre(const float* __restrict__ partT,
                                                const float* __restrict__ partG,
                                                float* __restrict__ tmpT,
                                                float* __restrict__ Gc,
                                                const float* __restrict__ Ve,
                                                __bf16* __restrict__ VeHi,
                                                __bf16* __restrict__ VeLo) {
    if (blockIdx.x >= 512) {
        int o = ((blockIdx.x - 512) * 128 + threadIdx.x) * 4;  // 0..262140
        int e0 = o & 7, lp = (o >> 3) & 63, tile = o >> 9;
        int kk = tile & 15, tt = tile >> 4;
        int t = tt * 16 + (lp & 15);
        int k = kk * 32 + (lp >> 4) * 8 + e0;
        f32x4 v = *(const f32x4*)&Ve[(size_t)t * T_N + k];
        bf16x4 h, lo;
#pragma unroll
        for (int j = 0; j < 4; ++j) {
            h[j] = (__bf16)v[j];
            lo[j] = (__bf16)(v[j] - (float)h[j]);
        }
        *(bf16x4*)&VeHi[o] = h;
        *(bf16x4*)&VeLo[o] = lo;
        return;
    }
    __shared__ f32x4 red[16][8];
    int oid = threadIdx.x & 15;               // 0..15 (fast -> contiguous)
    int seg = threadIdx.x >> 4;               // 0..7
    int o = blockIdx.x * 16 + oid;            // 0..8191
    int isG = o >> 12;
    int oo = o & 4095;                        // f32x4 slot in [32][128]
    int c = oo >> 7;
    int tq = oo & 127;                        // t = tq*4
    const float* src = isG ? partG : partT;
    size_t base = (size_t)c * T_N + tq * 4;
    f32x4 s = (f32x4)0.f;
#pragma unroll 4
    for (int vc = seg * 32; vc < seg * 32 + 32; ++vc)
        s += *(const f32x4*)&src[base + (size_t)vc * (C_N * T_N)];
    red[oid][seg] = s;
    __syncthreads();
    if (seg == 0) {
        f32x4 tot = red[oid][0];
#pragma unroll
        for (int k = 1; k < 8; ++k) tot += red[oid][k];
        float* dst = isG ? Gc : tmpT;
        *(f32x4*)&dst[c * T_N + tq * 4] = tot;
    }
}

// ---------------------------------------------------------------------------
// P[s][r] = sum_c Gc[c][s] * tmpT[c][r]    (K=32 tiny GEMM, fp32)
__global__ __launch_bounds__(256) void k_P2(const float* __restrict__ Gc,
                                            const float* __restrict__ tmpT,
                                            float* __restrict__ P) {
    __shared__ float Gs[32][64];
    __shared__ float Ts[32][64];
    int rbase = blockIdx.x * 64, sbase = blockIdx.y * 64;
    int tid = threadIdx.x;
    int tx = tid & 15, ty = tid >> 4;
    for (int i = tid; i < 2048; i += 256) {
        int cc = i >> 6, j = i & 63;
        Gs[cc][j] = Gc[cc * T_N + sbase + j];
        Ts[cc][j] = tmpT[cc * T_N + rbase + j];
    }
    __syncthreads();
    float acc[4][4] = {};
#pragma unroll
    for (int cc = 0; cc < 32; ++cc) {
        float a[4], b[4];
#pragma unroll
        for (int i = 0; i < 4; ++i) a[i] = Gs[cc][ty * 4 + i];
#pragma unroll
        for (int j = 0; j < 4; ++j) b[j] = Ts[cc][tx * 4 + j];
#pragma unroll
        for (int i = 0; i < 4; ++i)
#pragma unroll
            for (int j = 0; j < 4; ++j) acc[i][j] = fmaf(a[i], b[j], acc[i][j]);
    }
#pragma unroll
    for (int i = 0; i < 4; ++i) {
        f32x4 vv = {acc[i][0], acc[i][1], acc[i][2], acc[i][3]};
        *(f32x4*)&P[(size_t)(sbase + ty * 4 + i) * T_N + rbase + tx * 4] = vv;
    }
}

// ---------------------------------------------------------------------------
// Fused: per block (c, 32-wide r tile), all t (512 blocks, 2 blocks/CU):
//   S[s][r] = sigmoid(P[s][r] + be[c][s][r])   (bf16, LDS 32KB, XOR-swizzled)
//   E[t][r] = sum_s (VeHi+VeLo)[t][s] * S[s][r]  via MFMA 16x16x32 bf16
//   out[c][t][r] = softmax_t(E)
// NEW wave decomposition: 8 waves = 8 disjoint 64-t strips; each wave does
// acc[4 mi][2 ni] covering BOTH r-halves -> zero intra-block Ve-fragment
// duplication (was 2x: wr-pairs loaded identical ah/al). Ve L2 traffic
// halves: 2MB -> 1MB per block (1GB -> 512MB total).
__global__ __launch_bounds__(512, 4) void k_fused(const float* __restrict__ P,
                                                  const float* __restrict__ be,
                                                  const __bf16* __restrict__ VeHi,
                                                  const __bf16* __restrict__ VeLo,
                                                  float* __restrict__ out) {
    __shared__ __bf16 S[32][512];   // 32KB: S^T layout [r][s], swizzled
    const int rbase = blockIdx.x * 32;
    const int c = blockIdx.y;
    const int tid = threadIdx.x;
    const size_t cTT = (size_t)c * T_N * T_N;

    // ---- phase 1: sigmoid once per element (f32x4 loads), S^T bf16 swizzled
    {
        int r4 = (tid & 7) * 4;
        int s0 = tid >> 3;          // 0..63
        for (int i = 0; i < 8; ++i) {
            int s = i * 64 + s0;
            size_t off = (size_t)s * T_N + rbase + r4;
            f32x4 pv = *(const f32x4*)&P[off];
            f32x4 bv = *(const f32x4*)&be[cTT + off];
#pragma unroll
            for (int j = 0; j < 4; ++j) {
                float vv = pv[j] + bv[j];
                float sg = 1.0f / (1.0f + __expf(-vv));
                int rl = r4 + j;
                S[rl][s ^ ((rl & 7) << 3)] = (__bf16)sg;
            }
        }
    }
    __syncthreads();

    const int lane = tid & 63;
    const int w = tid >> 6;     // 0..7: 64-t strip index
    const int lhi = lane >> 4;  // 0..3
    const int llo = lane & 15;

    const bf16x8* fragHi = (const bf16x8*)VeHi;
    const bf16x8* fragLo = (const bf16x8*)VeLo;

    f32x4 acc[4][2];
#pragma unroll
    for (int mi = 0; mi < 4; ++mi)
#pragma unroll
        for (int ni = 0; ni < 2; ++ni) acc[mi][ni] = (f32x4)0.f;

    // ---- phase 2: K loop (s), A = packed Ve frags (L2-hot, deduped), B LDS
    for (int k0 = 0; k0 < T_N; k0 += 32) {
        bf16x8 b[2];
        int g = (k0 >> 3) + lhi;
#pragma unroll
        for (int ni = 0; ni < 2; ++ni) {
            int rr = ni * 16 + llo;
            b[ni] = *(const bf16x8*)&S[rr][(g ^ (rr & 7)) << 3];
        }
#pragma unroll
        for (int mi = 0; mi < 4; ++mi) {
            int tile = (w * 4 + mi) * 16 + (k0 >> 5);
            bf16x8 ah = fragHi[tile * 64 + lane];
            bf16x8 al = fragLo[tile * 64 + lane];
#pragma unroll
            for (int ni = 0; ni < 2; ++ni) {
                acc[mi][ni] = __builtin_amdgcn_mfma_f32_16x16x32_bf16(ah, b[ni], acc[mi][ni], 0, 0, 0);
                acc[mi][ni] = __builtin_amdgcn_mfma_f32_16x16x32_bf16(al, b[ni], acc[mi][ni], 0, 0, 0);
            }
        }
    }
    __syncthreads();            // done with S; reuse as reduction buffers

    float* red = (float*)&S[0][0];  // [0..255]=max, [256..511]=sum
    float gmax[2], gsum[2];

    // ---- phase 3a: column max over t (8 wave-partials per column)
#pragma unroll
    for (int ni = 0; ni < 2; ++ni) {
        float m = -3.4e38f;
#pragma unroll
        for (int mi = 0; mi < 4; ++mi)
#pragma unroll
            for (int q = 0; q < 4; ++q) m = fmaxf(m, acc[mi][ni][q]);
        m = fmaxf(m, __shfl_xor(m, 16));
        m = fmaxf(m, __shfl_xor(m, 32));
        if (lane < 16) red[w * 32 + ni * 16 + llo] = m;
    }
    __syncthreads();
#pragma unroll
    for (int ni = 0; ni < 2; ++ni) {
        int col = ni * 16 + llo;
        float m = red[col];
#pragma unroll
        for (int wv = 1; wv < 8; ++wv) m = fmaxf(m, red[wv * 32 + col]);
        gmax[ni] = m;
    }
    // ---- phase 3b: exp + column sum
#pragma unroll
    for (int ni = 0; ni < 2; ++ni) {
        float ssum = 0.f;
#pragma unroll
        for (int mi = 0; mi < 4; ++mi)
#pragma unroll
            for (int q = 0; q < 4; ++q) {
                float e = __expf(acc[mi][ni][q] - gmax[ni]);
                acc[mi][ni][q] = e;
                ssum += e;
            }
        ssum += __shfl_xor(ssum, 16);
        ssum += __shfl_xor(ssum, 32);
        if (lane < 16) red[256 + w * 32 + ni * 16 + llo] = ssum;
    }
    __syncthreads();
#pragma unroll
    for (int ni = 0; ni < 2; ++ni) {
        int col = ni * 16 + llo;
        float s = red[256 + col];
#pragma unroll
        for (int wv = 1; wv < 8; ++wv) s += red[256 + wv * 32 + col];
        gsum[ni] = 1.0f / s;
    }
    // ---- phase 3c: write normalized output
#pragma unroll
    for (int mi = 0; mi < 4; ++mi)
#pragma unroll
        for (int ni = 0; ni < 2; ++ni) {
            int rg = rbase + ni * 16 + llo;
#pragma unroll
            for (int q = 0; q < 4; ++q) {
                int t = w * 64 + mi * 16 + lhi * 4 + q;
                out[cTT + (size_t)t * T_N + rg] = acc[mi][ni][q] * gsum[ni];
            }
        }
}

// ---------------------------------------------------------------------------
extern "C" void kernel_launch(void* const* d_in, const int* in_sizes, int n_in,
                              void* d_out, int out_size, void* d_ws, size_t ws_size,
                              hipStream_t stream) {
    const float* x  = (const float*)d_in[0];
    const float* U1 = (const float*)d_in[1];
    const float* U2 = (const float*)d_in[2];
    const float* U3 = (const float*)d_in[3];
    const float* be = (const float*)d_in[4];
    const float* Ve = (const float*)d_in[5];
    float* out = (float*)d_out;

    float* ws    = (float*)d_ws;
    float* partT = ws;                        // 256*32*512 = 4194304 floats
    float* partG = ws + 4194304;              // 4194304
    float* P     = ws + 8388608;              // 262144
    __bf16* VeHi = (__bf16*)(ws + 8650752);   // 262144 bf16 (131072 slots)
    __bf16* VeLo = (__bf16*)(ws + 8781824);   // 262144 bf16
    float* tmpT  = ws + 8912896;              // 16384
    float* Gc    = ws + 8929280;              // 16384
    // total ~8945664 floats ~= 35.8 MB

    k_rt    <<<512, 256, 0, stream>>>(x, U1, U2, U3, partT, partG);
    k_redpre<<<512 + 512, 128, 0, stream>>>(partT, partG, tmpT, Gc, Ve, VeHi, VeLo);
    k_P2    <<<dim3(8, 8), 256, 0, stream>>>(Gc, tmpT, P);
    k_fused <<<dim3(16, C_N), 512, 0, stream>>>(P, be, VeHi, VeLo, out);
}